// Round 1
// baseline (552.458 us; speedup 1.0000x reference)
//
#include <hip/hip_runtime.h>
#include <float.h>

#define N_NODES   50000
#define N_EDGES   800000
#define INDIM1    128
#define HC        64
#define N_GRAPHS  64
#define NEG_SLOPE 0.2f

// ---------------- CSR build ----------------

__global__ __launch_bounds__(256) void hist_kernel(const int* __restrict__ dst,
                                                   int* __restrict__ deg) {
    int e = blockIdx.x * blockDim.x + threadIdx.x;
    if (e < N_EDGES) atomicAdd(&deg[dst[e]], 1);
}

__global__ __launch_bounds__(1024) void scan_kernel(const int* __restrict__ deg,
                                                    int* __restrict__ offsets) {
    __shared__ int tsum[1024];
    const int n = N_NODES;
    int t = threadIdx.x;
    int chunk = (n + 1023) / 1024;
    int b = t * chunk;
    int e = min(b + chunk, n);
    int s = 0;
    for (int i = b; i < e; ++i) s += deg[i];
    tsum[t] = s;
    __syncthreads();
    int val = s;
    for (int off = 1; off < 1024; off <<= 1) {
        int other = (t >= off) ? tsum[t - off] : 0;
        __syncthreads();
        val += other;
        tsum[t] = val;
        __syncthreads();
    }
    int run = val - s;           // exclusive prefix
    for (int i = b; i < e; ++i) { offsets[i] = run; run += deg[i]; }
    if (t == 1023) offsets[n] = run;   // == N_EDGES
}

// Denormalize edge data into CSR (dst-grouped) order: all later per-layer
// kernels get fully coalesced reads and the softmax needs no atomics.
__global__ __launch_bounds__(256) void scatter_kernel(const int* __restrict__ src,
                                                      const int* __restrict__ dst,
                                                      const float* __restrict__ eattr,
                                                      const int* __restrict__ offsets,
                                                      int* __restrict__ cursor,
                                                      int* __restrict__ csr_src,
                                                      int* __restrict__ csr_dst,
                                                      float* __restrict__ csr_ea) {
    int e = blockIdx.x * blockDim.x + threadIdx.x;
    if (e < N_EDGES) {
        int d = dst[e];
        int pos = offsets[d] + atomicAdd(&cursor[d], 1);
        csr_src[pos] = src[e];
        csr_dst[pos] = d;
        csr_ea[pos]  = eattr[e];
    }
}

// ---------------- per-layer kernels ----------------

// wedot[h] = dot(We[h*16:(h+1)*16], ae[h])  (edge_attr has 1 feature)
__global__ void wedot_kernel(const float* __restrict__ We, const float* __restrict__ ae,
                             float* __restrict__ wd) {
    int t = threadIdx.x;   // 64
    float p = We[t] * ae[t];
    for (int off = 1; off < 16; off <<= 1) p += __shfl_xor(p, off);
    if ((t & 15) == 0) wd[t >> 4] = p;
}

// xs = x @ W  (row-major W [INDIM,64]); also a_src/a_dst per (node, head).
// Block = 256 threads = 4 waves = 4 nodes; lane = output column (h*16+c).
template <int INDIM>
__global__ __launch_bounds__(256) void transform_kernel(const float* __restrict__ x,
                                                        const float* __restrict__ W,
                                                        const float* __restrict__ att_s,
                                                        const float* __restrict__ att_d,
                                                        float* __restrict__ xs,
                                                        float* __restrict__ a_src,
                                                        float* __restrict__ a_dst) {
    __shared__ float Wsh[INDIM * 64];
    __shared__ float xrow[4][INDIM];
    int t = threadIdx.x;
    for (int i = t; i < INDIM * 64; i += 256) Wsh[i] = W[i];
    int w = t >> 6, lane = t & 63;
    int node = blockIdx.x * 4 + w;
    if (node < N_NODES) {
        for (int k = lane; k < INDIM; k += 64) xrow[w][k] = x[node * INDIM + k];
    }
    __syncthreads();
    if (node >= N_NODES) return;
    float acc = 0.f;
#pragma unroll 8
    for (int k = 0; k < INDIM; ++k) acc = fmaf(xrow[w][k], Wsh[k * 64 + lane], acc);
    xs[node * 64 + lane] = acc;
    float ps = acc * att_s[lane];
    float pd = acc * att_d[lane];
    for (int off = 1; off < 16; off <<= 1) {
        ps += __shfl_xor(ps, off);
        pd += __shfl_xor(pd, off);
    }
    if ((lane & 15) == 0) {
        a_src[node * 4 + (lane >> 4)] = ps;
        a_dst[node * 4 + (lane >> 4)] = pd;
    }
}

// alpha[j][h] = leaky_relu(a_src[src_j][h] + a_dst[dst_j][h] + ea_j*wd[h]),
// stored in CSR order (coalesced float4 store).
__global__ __launch_bounds__(256) void edge_alpha_kernel(const int* __restrict__ csr_src,
                                                         const int* __restrict__ csr_dst,
                                                         const float* __restrict__ csr_ea,
                                                         const float* __restrict__ a_src,
                                                         const float* __restrict__ a_dst,
                                                         const float* __restrict__ wd,
                                                         float* __restrict__ alpha) {
    int j = blockIdx.x * blockDim.x + threadIdx.x;
    if (j >= N_EDGES) return;
    int s_ = csr_src[j];
    int d_ = csr_dst[j];
    float ea = csr_ea[j];
    float4 as = ((const float4*)a_src)[s_];
    float4 ad = ((const float4*)a_dst)[d_];
    float4 wv = *((const float4*)wd);
    float4 al;
    al.x = as.x + ad.x + ea * wv.x;
    al.y = as.y + ad.y + ea * wv.y;
    al.z = as.z + ad.z + ea * wv.z;
    al.w = as.w + ad.w + ea * wv.w;
    al.x = al.x > 0.f ? al.x : NEG_SLOPE * al.x;
    al.y = al.y > 0.f ? al.y : NEG_SLOPE * al.y;
    al.z = al.z > 0.f ? al.z : NEG_SLOPE * al.z;
    al.w = al.w > 0.f ? al.w : NEG_SLOPE * al.w;
    ((float4*)alpha)[j] = al;
}

// One wave per node: online softmax over incoming edges + weighted gather-sum.
// Lane = output channel (h*16+c). alpha/csr_src reads are coalesced (CSR order);
// xs[src] gather is a contiguous 256B wave read per edge.
__global__ __launch_bounds__(256) void aggregate_kernel(const float* __restrict__ xs,
                                                        const float* __restrict__ alpha,
                                                        const int* __restrict__ csr_src,
                                                        const int* __restrict__ offsets,
                                                        const float* __restrict__ bias,
                                                        float* __restrict__ outb,
                                                        int do_relu) {
    int w = threadIdx.x >> 6, lane = threadIdx.x & 63;
    int node = blockIdx.x * 4 + w;
    if (node >= N_NODES) return;
    int beg = offsets[node], end = offsets[node + 1];

    // --- online softmax (m, s) per head; lanes: j = lane>>2 stride 16, h = lane&3
    float m = -FLT_MAX, s = 0.f;
    {
        int h = lane & 3;
        for (int j = beg + (lane >> 2); j < end; j += 16) {
            float a = alpha[j * 4 + h];
            if (a > m) { s *= __expf(m - a); m = a; }
            s += __expf(a - m);
        }
    }
    // combine across lanes with the same (lane&3)
    for (int off = 4; off < 64; off <<= 1) {
        float mo = __shfl_xor(m, off);
        float so = __shfl_xor(s, off);
        float mn = fmaxf(m, mo);
        float sn = 0.f;
        if (s  > 0.f) sn += s  * __expf(m  - mn);
        if (so > 0.f) sn += so * __expf(mo - mn);
        m = mn; s = sn;
    }
    // lanes 0..3 hold heads 0..3
    int h2 = lane >> 4;
    float mh = __shfl(m, h2);
    float sh = __shfl(s, h2);

    // --- weighted aggregation
    float acc = 0.f;
    for (int j = beg; j < end; ++j) {
        float wgt = __expf(alpha[j * 4 + h2] - mh);
        acc = fmaf(wgt, xs[csr_src[j] * 64 + lane], acc);
    }
    float res = (sh > 0.f) ? acc / sh : 0.f;
    res += bias[lane];
    if (do_relu) res = fmaxf(res, 0.f);
    outb[node * 64 + lane] = res;
}

// ---------------- pooling ----------------

// batch is sorted; each wave handles 16 consecutive nodes, flushing an atomic
// only on graph-id change (~1 atomic set per wave instead of per node).
__global__ __launch_bounds__(256) void pool_kernel(const float* __restrict__ h,
                                                   const int* __restrict__ batch,
                                                   float* __restrict__ out,
                                                   int* __restrict__ cnt) {
    int wave = (blockIdx.x * blockDim.x + threadIdx.x) >> 6;
    int lane = threadIdx.x & 63;
    int i0 = wave * 16;
    if (i0 >= N_NODES) return;
    int i1 = min(i0 + 16, N_NODES);
    float acc = 0.f;
    int c = 0;
    int gcur = batch[i0];
    for (int i = i0; i < i1; ++i) {
        int g = batch[i];
        if (g != gcur) {
            atomicAdd(&out[gcur * 64 + lane], acc);
            if (lane == 0) atomicAdd(&cnt[gcur], c);
            acc = 0.f; c = 0; gcur = g;
        }
        acc += h[i * 64 + lane];
        ++c;
    }
    atomicAdd(&out[gcur * 64 + lane], acc);
    if (lane == 0) atomicAdd(&cnt[gcur], c);
}

__global__ void pool_div_kernel(float* __restrict__ out, const int* __restrict__ cnt) {
    int g = blockIdx.x, t = threadIdx.x;
    float c = (float)max(cnt[g], 1);
    out[g * 64 + t] /= c;
}

// ---------------- launch ----------------

extern "C" void kernel_launch(void* const* d_in, const int* in_sizes, int n_in,
                              void* d_out, int out_size, void* d_ws, size_t ws_size,
                              hipStream_t stream) {
    const float* x    = (const float*)d_in[0];
    const int*   eidx = (const int*)d_in[1];
    const float* eat  = (const float*)d_in[2];
    const int*   batch= (const int*)d_in[3];
    const float* W1   = (const float*)d_in[4];
    const float* We1  = (const float*)d_in[5];
    const float* as1  = (const float*)d_in[6];
    const float* ad1  = (const float*)d_in[7];
    const float* ae1  = (const float*)d_in[8];
    const float* b1   = (const float*)d_in[9];
    const float* W2   = (const float*)d_in[10];
    const float* We2  = (const float*)d_in[11];
    const float* as2  = (const float*)d_in[12];
    const float* ad2  = (const float*)d_in[13];
    const float* ae2  = (const float*)d_in[14];
    const float* b2   = (const float*)d_in[15];
    const int* src  = eidx;             // edge_index[0]
    const int* dstp = eidx + N_EDGES;   // edge_index[1]
    float* out = (float*)d_out;

    char* p = (char*)d_ws;
    auto alloc = [&](size_t bytes) {
        char* r = p;
        p += (bytes + 255) & ~(size_t)255;
        return r;
    };
    float* xs     = (float*)alloc((size_t)N_NODES * 64 * 4);
    float* hbuf   = (float*)alloc((size_t)N_NODES * 64 * 4);
    float* asrc   = (float*)alloc((size_t)N_NODES * 4 * 4);
    float* adst   = (float*)alloc((size_t)N_NODES * 4 * 4);
    float* alpha  = (float*)alloc((size_t)N_EDGES * 4 * 4);
    float* wd1    = (float*)alloc(64);
    float* wd2    = (float*)alloc(64);
    int*   deg    = (int*)alloc((size_t)N_NODES * 4);
    int*   offs   = (int*)alloc((size_t)(N_NODES + 1) * 4);
    int*   cur    = (int*)alloc((size_t)N_NODES * 4);
    int*   csrsrc = (int*)alloc((size_t)N_EDGES * 4);
    int*   csrdst = (int*)alloc((size_t)N_EDGES * 4);
    float* csrea  = (float*)alloc((size_t)N_EDGES * 4);
    int*   cnt    = (int*)alloc(64 * 4);

    hipMemsetAsync(deg, 0, (size_t)N_NODES * 4, stream);
    hipMemsetAsync(cur, 0, (size_t)N_NODES * 4, stream);
    hipMemsetAsync(cnt, 0, 64 * 4, stream);
    hipMemsetAsync(d_out, 0, (size_t)N_GRAPHS * 64 * 4, stream);

    const int EB = (N_EDGES + 255) / 256;
    const int NB = (N_NODES + 3) / 4;

    hist_kernel<<<EB, 256, 0, stream>>>(dstp, deg);
    scan_kernel<<<1, 1024, 0, stream>>>(deg, offs);
    scatter_kernel<<<EB, 256, 0, stream>>>(src, dstp, eat, offs, cur, csrsrc, csrdst, csrea);
    wedot_kernel<<<1, 64, 0, stream>>>(We1, ae1, wd1);
    wedot_kernel<<<1, 64, 0, stream>>>(We2, ae2, wd2);

    // layer 1
    transform_kernel<INDIM1><<<NB, 256, 0, stream>>>(x, W1, as1, ad1, xs, asrc, adst);
    edge_alpha_kernel<<<EB, 256, 0, stream>>>(csrsrc, csrdst, csrea, asrc, adst, wd1, alpha);
    aggregate_kernel<<<NB, 256, 0, stream>>>(xs, alpha, csrsrc, offs, b1, hbuf, 1);

    // layer 2
    transform_kernel<HC><<<NB, 256, 0, stream>>>(hbuf, W2, as2, ad2, xs, asrc, adst);
    edge_alpha_kernel<<<EB, 256, 0, stream>>>(csrsrc, csrdst, csrea, asrc, adst, wd2, alpha);
    aggregate_kernel<<<NB, 256, 0, stream>>>(xs, alpha, csrsrc, offs, b2, hbuf, 0);

    // mean pool
    int pool_waves = (N_NODES + 15) / 16;
    int pool_blocks = (pool_waves + 3) / 4;
    pool_kernel<<<pool_blocks, 256, 0, stream>>>(hbuf, batch, out, cnt);
    pool_div_kernel<<<N_GRAPHS, 64, 0, stream>>>(out, cnt);
}

// Round 2
// 478.679 us; speedup vs baseline: 1.1541x; 1.1541x over previous
//
#include <hip/hip_runtime.h>
#include <float.h>

#define N_NODES   50000
#define N_EDGES   800000
#define INDIM1    128
#define HC        64
#define N_GRAPHS  64
#define NEG_SLOPE 0.2f

// ---------------- CSR build ----------------

__global__ __launch_bounds__(256) void hist_kernel(const int* __restrict__ dst,
                                                   int* __restrict__ deg) {
    int e = blockIdx.x * blockDim.x + threadIdx.x;
    if (e < N_EDGES) atomicAdd(&deg[dst[e]], 1);
}

__global__ __launch_bounds__(1024) void scan_kernel(const int* __restrict__ deg,
                                                    int* __restrict__ offsets) {
    __shared__ int tsum[1024];
    const int n = N_NODES;
    int t = threadIdx.x;
    int chunk = (n + 1023) / 1024;
    int b = t * chunk;
    int e = min(b + chunk, n);
    int s = 0;
    for (int i = b; i < e; ++i) s += deg[i];
    tsum[t] = s;
    __syncthreads();
    int val = s;
    for (int off = 1; off < 1024; off <<= 1) {
        int other = (t >= off) ? tsum[t - off] : 0;
        __syncthreads();
        val += other;
        tsum[t] = val;
        __syncthreads();
    }
    int run = val - s;           // exclusive prefix
    for (int i = b; i < e; ++i) { offsets[i] = run; run += deg[i]; }
    if (t == 1023) offsets[n] = run;   // == N_EDGES
}

__global__ __launch_bounds__(256) void scatter_kernel(const int* __restrict__ src,
                                                      const int* __restrict__ dst,
                                                      const float* __restrict__ eattr,
                                                      const int* __restrict__ offsets,
                                                      int* __restrict__ cursor,
                                                      int* __restrict__ csr_src,
                                                      int* __restrict__ csr_dst,
                                                      float* __restrict__ csr_ea) {
    int e = blockIdx.x * blockDim.x + threadIdx.x;
    if (e < N_EDGES) {
        int d = dst[e];
        int pos = offsets[d] + atomicAdd(&cursor[d], 1);
        csr_src[pos] = src[e];
        csr_dst[pos] = d;
        csr_ea[pos]  = eattr[e];
    }
}

// ---------------- per-layer kernels ----------------

__global__ void wedot_kernel(const float* __restrict__ We, const float* __restrict__ ae,
                             float* __restrict__ wd) {
    int t = threadIdx.x;   // 64
    float p = We[t] * ae[t];
    for (int off = 1; off < 16; off <<= 1) p += __shfl_xor(p, off);
    if ((t & 15) == 0) wd[t >> 4] = p;
}

// xs = x @ W; a_src/a_dst per (node, head).
// Block = 256 = 4 waves; each wave handles NPW nodes; W staged once per block
// as float4 [k/4][col] so the inner loop is ds_read_b128 (4 k's per LDS instr).
template <int INDIM, int NPW>
__global__ __launch_bounds__(256) void transform_kernel(const float* __restrict__ x,
                                                        const float* __restrict__ W,
                                                        const float* __restrict__ att_s,
                                                        const float* __restrict__ att_d,
                                                        float* __restrict__ xs,
                                                        float* __restrict__ a_src,
                                                        float* __restrict__ a_dst) {
    constexpr int K4 = INDIM / 4;
    __shared__ float4 Wsh[K4 * 64];     // [k4][col]
    __shared__ float4 xsh[4][K4];       // per-wave current x row
    int t = threadIdx.x;
    for (int i = t; i < K4 * 64; i += 256) {
        int k4 = i >> 6, col = i & 63;
        Wsh[i] = make_float4(W[(4 * k4 + 0) * 64 + col], W[(4 * k4 + 1) * 64 + col],
                             W[(4 * k4 + 2) * 64 + col], W[(4 * k4 + 3) * 64 + col]);
    }
    __syncthreads();
    int w = t >> 6, lane = t & 63;
    float avs = att_s[lane], avd = att_d[lane];
    int node0 = blockIdx.x * (4 * NPW) + w * NPW;
    for (int ni = 0; ni < NPW; ++ni) {
        int node = node0 + ni;
        if (node >= N_NODES) return;   // wave-uniform
        if (lane < K4) xsh[w][lane] = ((const float4*)(x + (size_t)node * INDIM))[lane];
        float acc = 0.f;
#pragma unroll
        for (int k4 = 0; k4 < K4; ++k4) {
            float4 xv = xsh[w][k4];
            float4 wv = Wsh[k4 * 64 + lane];
            acc = fmaf(xv.x, wv.x, acc);
            acc = fmaf(xv.y, wv.y, acc);
            acc = fmaf(xv.z, wv.z, acc);
            acc = fmaf(xv.w, wv.w, acc);
        }
        xs[(size_t)node * 64 + lane] = acc;
        float ps = acc * avs;
        float pd = acc * avd;
        for (int off = 1; off < 16; off <<= 1) {
            ps += __shfl_xor(ps, off);
            pd += __shfl_xor(pd, off);
        }
        if ((lane & 15) == 0) {
            a_src[node * 4 + (lane >> 4)] = ps;
            a_dst[node * 4 + (lane >> 4)] = pd;
        }
    }
}

__global__ __launch_bounds__(256) void edge_alpha_kernel(const int* __restrict__ csr_src,
                                                         const int* __restrict__ csr_dst,
                                                         const float* __restrict__ csr_ea,
                                                         const float* __restrict__ a_src,
                                                         const float* __restrict__ a_dst,
                                                         const float* __restrict__ wd,
                                                         float* __restrict__ alpha) {
    int j = blockIdx.x * blockDim.x + threadIdx.x;
    if (j >= N_EDGES) return;
    int s_ = csr_src[j];
    int d_ = csr_dst[j];
    float ea = csr_ea[j];
    float4 as = ((const float4*)a_src)[s_];
    float4 ad = ((const float4*)a_dst)[d_];
    float4 wv = *((const float4*)wd);
    float4 al;
    al.x = as.x + ad.x + ea * wv.x;
    al.y = as.y + ad.y + ea * wv.y;
    al.z = as.z + ad.z + ea * wv.z;
    al.w = as.w + ad.w + ea * wv.w;
    al.x = al.x > 0.f ? al.x : NEG_SLOPE * al.x;
    al.y = al.y > 0.f ? al.y : NEG_SLOPE * al.y;
    al.z = al.z > 0.f ? al.z : NEG_SLOPE * al.z;
    al.w = al.w > 0.f ? al.w : NEG_SLOPE * al.w;
    ((float4*)alpha)[j] = al;
}

// One wave per node, chunked 16 edges at a time; fused online softmax +
// weighted gather. Per chunk: one coalesced 256B alpha load (lane=(e,h)),
// one 64B csr_src load, chunk-max shfl reduce, then 16 INDEPENDENT xs row
// gathers (unrolled) — removes the serial per-edge dependent-load chain.
__global__ __launch_bounds__(256) void aggregate_kernel(const float* __restrict__ xs,
                                                        const float* __restrict__ alpha,
                                                        const int* __restrict__ csr_src,
                                                        const int* __restrict__ offsets,
                                                        const float* __restrict__ bias,
                                                        float* __restrict__ outb,
                                                        int do_relu) {
    int w = threadIdx.x >> 6, lane = threadIdx.x & 63;
    int node = blockIdx.x * 4 + w;
    if (node >= N_NODES) return;
    int beg = offsets[node], end = offsets[node + 1];
    const int e_idx = lane >> 2;   // 0..15: edge slot in chunk
    const int h2 = lane >> 4;      // my output head (channel = lane & 15)

    float m = -FLT_MAX;            // running max, head (lane&3) — uniform across same-h lanes
    float s = 0.f;                 // partial weight sum (this lane's slots)
    float acc = 0.f;               // output accumulator, head h2

    for (int j0 = beg; j0 < end; j0 += 16) {
        int j = j0 + e_idx;
        bool v = (j < end);
        int aidx = j0 * 4 + lane;                   // == j*4 + (lane&3), contiguous
        float a = v ? alpha[aidx] : -FLT_MAX;
        int srcv = v ? csr_src[j] : 0;
        // chunk max per head over the 16 e-slots
        float cm = a;
        cm = fmaxf(cm, __shfl_xor(cm, 4));
        cm = fmaxf(cm, __shfl_xor(cm, 8));
        cm = fmaxf(cm, __shfl_xor(cm, 16));
        cm = fmaxf(cm, __shfl_xor(cm, 32));
        float mn = fmaxf(m, cm);
        float sc = __expf(m - mn);                  // rescale old state (0 on first chunk)
        float wgt = __expf(a - mn);                 // 0 for invalid slots
        s = s * sc + wgt;
        m = mn;
        acc *= __shfl(sc, h2);
        int nv = end - j0;
        if (nv >= 16) {
#pragma unroll
            for (int e = 0; e < 16; ++e) {
                float wg = __shfl(wgt, (e << 2) | h2);
                int sv = __shfl(srcv, e << 2);
                acc = fmaf(wg, xs[(size_t)sv * 64 + lane], acc);
            }
        } else {
            for (int e = 0; e < nv; ++e) {
                float wg = __shfl(wgt, (e << 2) | h2);
                int sv = __shfl(srcv, e << 2);
                acc = fmaf(wg, xs[(size_t)sv * 64 + lane], acc);
            }
        }
    }
    // total weight sum per head
    s += __shfl_xor(s, 4);
    s += __shfl_xor(s, 8);
    s += __shfl_xor(s, 16);
    s += __shfl_xor(s, 32);
    float sh = __shfl(s, h2);
    float res = (sh > 0.f) ? acc / sh : 0.f;
    res += bias[lane];
    if (do_relu) res = fmaxf(res, 0.f);
    outb[(size_t)node * 64 + lane] = res;
}

// ---------------- pooling ----------------

__global__ __launch_bounds__(256) void pool_kernel(const float* __restrict__ h,
                                                   const int* __restrict__ batch,
                                                   float* __restrict__ out,
                                                   int* __restrict__ cnt) {
    int wave = (blockIdx.x * blockDim.x + threadIdx.x) >> 6;
    int lane = threadIdx.x & 63;
    int i0 = wave * 16;
    if (i0 >= N_NODES) return;
    int i1 = min(i0 + 16, N_NODES);
    float acc = 0.f;
    int c = 0;
    int gcur = batch[i0];
    for (int i = i0; i < i1; ++i) {
        int g = batch[i];
        if (g != gcur) {
            atomicAdd(&out[gcur * 64 + lane], acc);
            if (lane == 0) atomicAdd(&cnt[gcur], c);
            acc = 0.f; c = 0; gcur = g;
        }
        acc += h[i * 64 + lane];
        ++c;
    }
    atomicAdd(&out[gcur * 64 + lane], acc);
    if (lane == 0) atomicAdd(&cnt[gcur], c);
}

__global__ void pool_div_kernel(float* __restrict__ out, const int* __restrict__ cnt) {
    int g = blockIdx.x, t = threadIdx.x;
    float c = (float)max(cnt[g], 1);
    out[g * 64 + t] /= c;
}

// ---------------- launch ----------------

extern "C" void kernel_launch(void* const* d_in, const int* in_sizes, int n_in,
                              void* d_out, int out_size, void* d_ws, size_t ws_size,
                              hipStream_t stream) {
    const float* x    = (const float*)d_in[0];
    const int*   eidx = (const int*)d_in[1];
    const float* eat  = (const float*)d_in[2];
    const int*   batch= (const int*)d_in[3];
    const float* W1   = (const float*)d_in[4];
    const float* We1  = (const float*)d_in[5];
    const float* as1  = (const float*)d_in[6];
    const float* ad1  = (const float*)d_in[7];
    const float* ae1  = (const float*)d_in[8];
    const float* b1   = (const float*)d_in[9];
    const float* W2   = (const float*)d_in[10];
    const float* We2  = (const float*)d_in[11];
    const float* as2  = (const float*)d_in[12];
    const float* ad2  = (const float*)d_in[13];
    const float* ae2  = (const float*)d_in[14];
    const float* b2   = (const float*)d_in[15];
    const int* src  = eidx;             // edge_index[0]
    const int* dstp = eidx + N_EDGES;   // edge_index[1]
    float* out = (float*)d_out;

    char* p = (char*)d_ws;
    auto alloc = [&](size_t bytes) {
        char* r = p;
        p += (bytes + 255) & ~(size_t)255;
        return r;
    };
    float* xs     = (float*)alloc((size_t)N_NODES * 64 * 4);
    float* hbuf   = (float*)alloc((size_t)N_NODES * 64 * 4);
    float* asrc   = (float*)alloc((size_t)N_NODES * 4 * 4);
    float* adst   = (float*)alloc((size_t)N_NODES * 4 * 4);
    float* alpha  = (float*)alloc((size_t)N_EDGES * 4 * 4);
    float* wd1    = (float*)alloc(64);
    float* wd2    = (float*)alloc(64);
    int*   deg    = (int*)alloc((size_t)N_NODES * 4);
    int*   offs   = (int*)alloc((size_t)(N_NODES + 1) * 4);
    int*   cur    = (int*)alloc((size_t)N_NODES * 4);
    int*   csrsrc = (int*)alloc((size_t)N_EDGES * 4);
    int*   csrdst = (int*)alloc((size_t)N_EDGES * 4);
    float* csrea  = (float*)alloc((size_t)N_EDGES * 4);
    int*   cnt    = (int*)alloc(64 * 4);

    hipMemsetAsync(deg, 0, (size_t)N_NODES * 4, stream);
    hipMemsetAsync(cur, 0, (size_t)N_NODES * 4, stream);
    hipMemsetAsync(cnt, 0, 64 * 4, stream);
    hipMemsetAsync(d_out, 0, (size_t)N_GRAPHS * 64 * 4, stream);

    const int EB = (N_EDGES + 255) / 256;
    const int NB = (N_NODES + 3) / 4;

    hist_kernel<<<EB, 256, 0, stream>>>(dstp, deg);
    scan_kernel<<<1, 1024, 0, stream>>>(deg, offs);
    scatter_kernel<<<EB, 256, 0, stream>>>(src, dstp, eat, offs, cur, csrsrc, csrdst, csrea);
    wedot_kernel<<<1, 64, 0, stream>>>(We1, ae1, wd1);
    wedot_kernel<<<1, 64, 0, stream>>>(We2, ae2, wd2);

    // layer 1  (32 nodes per block: 1563 blocks)
    const int NPW = 8;
    const int TB = (N_NODES + 4 * NPW - 1) / (4 * NPW);
    transform_kernel<INDIM1, NPW><<<TB, 256, 0, stream>>>(x, W1, as1, ad1, xs, asrc, adst);
    edge_alpha_kernel<<<EB, 256, 0, stream>>>(csrsrc, csrdst, csrea, asrc, adst, wd1, alpha);
    aggregate_kernel<<<NB, 256, 0, stream>>>(xs, alpha, csrsrc, offs, b1, hbuf, 1);

    // layer 2
    transform_kernel<HC, NPW><<<TB, 256, 0, stream>>>(hbuf, W2, as2, ad2, xs, asrc, adst);
    edge_alpha_kernel<<<EB, 256, 0, stream>>>(csrsrc, csrdst, csrea, asrc, adst, wd2, alpha);
    aggregate_kernel<<<NB, 256, 0, stream>>>(xs, alpha, csrsrc, offs, b2, hbuf, 0);

    // mean pool
    int pool_waves = (N_NODES + 15) / 16;
    int pool_blocks = (pool_waves + 3) / 4;
    pool_kernel<<<pool_blocks, 256, 0, stream>>>(hbuf, batch, out, cnt);
    pool_div_kernel<<<N_GRAPHS, 64, 0, stream>>>(out, cnt);
}

// Round 3
// 422.311 us; speedup vs baseline: 1.3082x; 1.1335x over previous
//
#include <hip/hip_runtime.h>
#include <float.h>

#define N_NODES   50000
#define N_EDGES   800000
#define INDIM1    128
#define HC        64
#define N_GRAPHS  64
#define NEG_SLOPE 0.2f

// ---------------- CSR build ----------------

__global__ __launch_bounds__(256) void hist_kernel(const int* __restrict__ dst,
                                                   int* __restrict__ deg) {
    int e = blockIdx.x * blockDim.x + threadIdx.x;
    if (e < N_EDGES) atomicAdd(&deg[dst[e]], 1);
}

// Assign each node a contiguous edge range [beg, beg+deg) in ARBITRARY node
// order: per-wave inclusive shfl-scan of deg, one atomicAdd per wave for the
// base. Replaces the 76us single-block serial scan (~0.15% occupancy) with a
// fully parallel ~3us kernel — range ORDER is irrelevant to correctness.
__global__ __launch_bounds__(256) void alloc_kernel(const int* __restrict__ deg,
                                                    int* __restrict__ beg,
                                                    int* __restrict__ gcounter) {
    int i = blockIdx.x * blockDim.x + threadIdx.x;
    int lane = threadIdx.x & 63;
    int d = (i < N_NODES) ? deg[i] : 0;
    int pre = d;                       // inclusive scan over the wave
    for (int off = 1; off < 64; off <<= 1) {
        int o = __shfl_up(pre, off);
        if (lane >= off) pre += o;
    }
    int total = __shfl(pre, 63);
    int base = 0;
    if (lane == 63) base = atomicAdd(gcounter, total);
    base = __shfl(base, 63);
    if (i < N_NODES) beg[i] = base + pre - d;
}

__global__ __launch_bounds__(256) void scatter_kernel(const int* __restrict__ src,
                                                      const int* __restrict__ dst,
                                                      const float* __restrict__ eattr,
                                                      const int* __restrict__ beg,
                                                      int* __restrict__ cursor,
                                                      int* __restrict__ csr_src,
                                                      int* __restrict__ csr_dst,
                                                      float* __restrict__ csr_ea) {
    int e = blockIdx.x * blockDim.x + threadIdx.x;
    if (e < N_EDGES) {
        int d = dst[e];
        int pos = beg[d] + atomicAdd(&cursor[d], 1);
        csr_src[pos] = src[e];
        csr_dst[pos] = d;
        csr_ea[pos]  = eattr[e];
    }
}

// ---------------- per-layer kernels ----------------

__global__ void wedot_kernel(const float* __restrict__ We, const float* __restrict__ ae,
                             float* __restrict__ wd) {
    int t = threadIdx.x;   // 64
    float p = We[t] * ae[t];
    for (int off = 1; off < 16; off <<= 1) p += __shfl_xor(p, off);
    if ((t & 15) == 0) wd[t >> 4] = p;
}

// xs = x @ W; a_src/a_dst per (node, head).
template <int INDIM, int NPW>
__global__ __launch_bounds__(256) void transform_kernel(const float* __restrict__ x,
                                                        const float* __restrict__ W,
                                                        const float* __restrict__ att_s,
                                                        const float* __restrict__ att_d,
                                                        float* __restrict__ xs,
                                                        float* __restrict__ a_src,
                                                        float* __restrict__ a_dst) {
    constexpr int K4 = INDIM / 4;
    __shared__ float4 Wsh[K4 * 64];     // [k4][col]
    __shared__ float4 xsh[4][K4];       // per-wave current x row
    int t = threadIdx.x;
    for (int i = t; i < K4 * 64; i += 256) {
        int k4 = i >> 6, col = i & 63;
        Wsh[i] = make_float4(W[(4 * k4 + 0) * 64 + col], W[(4 * k4 + 1) * 64 + col],
                             W[(4 * k4 + 2) * 64 + col], W[(4 * k4 + 3) * 64 + col]);
    }
    __syncthreads();
    int w = t >> 6, lane = t & 63;
    float avs = att_s[lane], avd = att_d[lane];
    int node0 = blockIdx.x * (4 * NPW) + w * NPW;
    for (int ni = 0; ni < NPW; ++ni) {
        int node = node0 + ni;
        if (node >= N_NODES) return;   // wave-uniform
        if (lane < K4) xsh[w][lane] = ((const float4*)(x + (size_t)node * INDIM))[lane];
        float acc = 0.f;
#pragma unroll
        for (int k4 = 0; k4 < K4; ++k4) {
            float4 xv = xsh[w][k4];
            float4 wv = Wsh[k4 * 64 + lane];
            acc = fmaf(xv.x, wv.x, acc);
            acc = fmaf(xv.y, wv.y, acc);
            acc = fmaf(xv.z, wv.z, acc);
            acc = fmaf(xv.w, wv.w, acc);
        }
        xs[(size_t)node * 64 + lane] = acc;
        float ps = acc * avs;
        float pd = acc * avd;
        for (int off = 1; off < 16; off <<= 1) {
            ps += __shfl_xor(ps, off);
            pd += __shfl_xor(pd, off);
        }
        if ((lane & 15) == 0) {
            a_src[node * 4 + (lane >> 4)] = ps;
            a_dst[node * 4 + (lane >> 4)] = pd;
        }
    }
}

__global__ __launch_bounds__(256) void edge_alpha_kernel(const int* __restrict__ csr_src,
                                                         const int* __restrict__ csr_dst,
                                                         const float* __restrict__ csr_ea,
                                                         const float* __restrict__ a_src,
                                                         const float* __restrict__ a_dst,
                                                         const float* __restrict__ wd,
                                                         float* __restrict__ alpha) {
    int j = blockIdx.x * blockDim.x + threadIdx.x;
    if (j >= N_EDGES) return;
    int s_ = csr_src[j];
    int d_ = csr_dst[j];
    float ea = csr_ea[j];
    float4 as = ((const float4*)a_src)[s_];
    float4 ad = ((const float4*)a_dst)[d_];
    float4 wv = *((const float4*)wd);
    float4 al;
    al.x = as.x + ad.x + ea * wv.x;
    al.y = as.y + ad.y + ea * wv.y;
    al.z = as.z + ad.z + ea * wv.z;
    al.w = as.w + ad.w + ea * wv.w;
    al.x = al.x > 0.f ? al.x : NEG_SLOPE * al.x;
    al.y = al.y > 0.f ? al.y : NEG_SLOPE * al.y;
    al.z = al.z > 0.f ? al.z : NEG_SLOPE * al.z;
    al.w = al.w > 0.f ? al.w : NEG_SLOPE * al.w;
    ((float4*)alpha)[j] = al;
}

// One wave per node, chunked 16 edges at a time; fused online softmax +
// weighted gather (16 independent xs row gathers in flight per chunk).
__global__ __launch_bounds__(256) void aggregate_kernel(const float* __restrict__ xs,
                                                        const float* __restrict__ alpha,
                                                        const int* __restrict__ csr_src,
                                                        const int* __restrict__ beg_arr,
                                                        const int* __restrict__ deg,
                                                        const float* __restrict__ bias,
                                                        float* __restrict__ outb,
                                                        int do_relu) {
    int w = threadIdx.x >> 6, lane = threadIdx.x & 63;
    int node = blockIdx.x * 4 + w;
    if (node >= N_NODES) return;
    int beg = beg_arr[node], end = beg + deg[node];
    const int e_idx = lane >> 2;   // 0..15: edge slot in chunk
    const int h2 = lane >> 4;      // my output head (channel = lane & 15)

    float m = -FLT_MAX;            // running max, head (lane&3)
    float s = 0.f;                 // partial weight sum (this lane's slots)
    float acc = 0.f;               // output accumulator, head h2

    for (int j0 = beg; j0 < end; j0 += 16) {
        int j = j0 + e_idx;
        bool v = (j < end);
        int aidx = j0 * 4 + lane;                   // == j*4 + (lane&3), contiguous
        float a = v ? alpha[aidx] : -FLT_MAX;
        int srcv = v ? csr_src[j] : 0;
        float cm = a;
        cm = fmaxf(cm, __shfl_xor(cm, 4));
        cm = fmaxf(cm, __shfl_xor(cm, 8));
        cm = fmaxf(cm, __shfl_xor(cm, 16));
        cm = fmaxf(cm, __shfl_xor(cm, 32));
        float mn = fmaxf(m, cm);
        float sc = __expf(m - mn);                  // rescale old state
        float wgt = __expf(a - mn);                 // 0 for invalid slots
        s = s * sc + wgt;
        m = mn;
        acc *= __shfl(sc, h2);
        int nv = end - j0;
        if (nv >= 16) {
#pragma unroll
            for (int e = 0; e < 16; ++e) {
                float wg = __shfl(wgt, (e << 2) | h2);
                int sv = __shfl(srcv, e << 2);
                acc = fmaf(wg, xs[(size_t)sv * 64 + lane], acc);
            }
        } else {
            for (int e = 0; e < nv; ++e) {
                float wg = __shfl(wgt, (e << 2) | h2);
                int sv = __shfl(srcv, e << 2);
                acc = fmaf(wg, xs[(size_t)sv * 64 + lane], acc);
            }
        }
    }
    s += __shfl_xor(s, 4);
    s += __shfl_xor(s, 8);
    s += __shfl_xor(s, 16);
    s += __shfl_xor(s, 32);
    float sh = __shfl(s, h2);
    float res = (sh > 0.f) ? acc / sh : 0.f;
    res += bias[lane];
    if (do_relu) res = fmaxf(res, 0.f);
    outb[(size_t)node * 64 + lane] = res;
}

// ---------------- pooling ----------------

__global__ __launch_bounds__(256) void pool_kernel(const float* __restrict__ h,
                                                   const int* __restrict__ batch,
                                                   float* __restrict__ out,
                                                   int* __restrict__ cnt) {
    int wave = (blockIdx.x * blockDim.x + threadIdx.x) >> 6;
    int lane = threadIdx.x & 63;
    int i0 = wave * 16;
    if (i0 >= N_NODES) return;
    int i1 = min(i0 + 16, N_NODES);
    float acc = 0.f;
    int c = 0;
    int gcur = batch[i0];
    for (int i = i0; i < i1; ++i) {
        int g = batch[i];
        if (g != gcur) {
            atomicAdd(&out[gcur * 64 + lane], acc);
            if (lane == 0) atomicAdd(&cnt[gcur], c);
            acc = 0.f; c = 0; gcur = g;
        }
        acc += h[i * 64 + lane];
        ++c;
    }
    atomicAdd(&out[gcur * 64 + lane], acc);
    if (lane == 0) atomicAdd(&cnt[gcur], c);
}

__global__ void pool_div_kernel(float* __restrict__ out, const int* __restrict__ cnt) {
    int g = blockIdx.x, t = threadIdx.x;
    float c = (float)max(cnt[g], 1);
    out[g * 64 + t] /= c;
}

// ---------------- launch ----------------

extern "C" void kernel_launch(void* const* d_in, const int* in_sizes, int n_in,
                              void* d_out, int out_size, void* d_ws, size_t ws_size,
                              hipStream_t stream) {
    const float* x    = (const float*)d_in[0];
    const int*   eidx = (const int*)d_in[1];
    const float* eat  = (const float*)d_in[2];
    const int*   batch= (const int*)d_in[3];
    const float* W1   = (const float*)d_in[4];
    const float* We1  = (const float*)d_in[5];
    const float* as1  = (const float*)d_in[6];
    const float* ad1  = (const float*)d_in[7];
    const float* ae1  = (const float*)d_in[8];
    const float* b1   = (const float*)d_in[9];
    const float* W2   = (const float*)d_in[10];
    const float* We2  = (const float*)d_in[11];
    const float* as2  = (const float*)d_in[12];
    const float* ad2  = (const float*)d_in[13];
    const float* ae2  = (const float*)d_in[14];
    const float* b2   = (const float*)d_in[15];
    const int* src  = eidx;             // edge_index[0]
    const int* dstp = eidx + N_EDGES;   // edge_index[1]
    float* out = (float*)d_out;

    char* p = (char*)d_ws;
    auto alloc = [&](size_t bytes) {
        char* r = p;
        p += (bytes + 255) & ~(size_t)255;
        return r;
    };
    float* xs     = (float*)alloc((size_t)N_NODES * 64 * 4);
    float* hbuf   = (float*)alloc((size_t)N_NODES * 64 * 4);
    float* asrc   = (float*)alloc((size_t)N_NODES * 4 * 4);
    float* adst   = (float*)alloc((size_t)N_NODES * 4 * 4);
    float* alpha  = (float*)alloc((size_t)N_EDGES * 4 * 4);
    float* wd1    = (float*)alloc(64);
    float* wd2    = (float*)alloc(64);
    int*   deg    = (int*)alloc((size_t)N_NODES * 4);
    int*   offs   = (int*)alloc((size_t)N_NODES * 4);
    int*   cur    = (int*)alloc((size_t)N_NODES * 4);
    int*   csrsrc = (int*)alloc((size_t)N_EDGES * 4);
    int*   csrdst = (int*)alloc((size_t)N_EDGES * 4);
    float* csrea  = (float*)alloc((size_t)N_EDGES * 4);
    int*   cnt    = (int*)alloc(64 * 4);
    int*   gctr   = (int*)alloc(256);

    hipMemsetAsync(deg, 0, (size_t)N_NODES * 4, stream);
    hipMemsetAsync(cur, 0, (size_t)N_NODES * 4, stream);
    hipMemsetAsync(cnt, 0, 64 * 4, stream);
    hipMemsetAsync(gctr, 0, 256, stream);
    hipMemsetAsync(d_out, 0, (size_t)N_GRAPHS * 64 * 4, stream);

    const int EB = (N_EDGES + 255) / 256;
    const int NB = (N_NODES + 3) / 4;
    const int AB = (N_NODES + 255) / 256;

    hist_kernel<<<EB, 256, 0, stream>>>(dstp, deg);
    alloc_kernel<<<AB, 256, 0, stream>>>(deg, offs, gctr);
    scatter_kernel<<<EB, 256, 0, stream>>>(src, dstp, eat, offs, cur, csrsrc, csrdst, csrea);
    wedot_kernel<<<1, 64, 0, stream>>>(We1, ae1, wd1);
    wedot_kernel<<<1, 64, 0, stream>>>(We2, ae2, wd2);

    // layer 1
    const int NPW = 8;
    const int TB = (N_NODES + 4 * NPW - 1) / (4 * NPW);
    transform_kernel<INDIM1, NPW><<<TB, 256, 0, stream>>>(x, W1, as1, ad1, xs, asrc, adst);
    edge_alpha_kernel<<<EB, 256, 0, stream>>>(csrsrc, csrdst, csrea, asrc, adst, wd1, alpha);
    aggregate_kernel<<<NB, 256, 0, stream>>>(xs, alpha, csrsrc, offs, deg, b1, hbuf, 1);

    // layer 2
    transform_kernel<HC, NPW><<<TB, 256, 0, stream>>>(hbuf, W2, as2, ad2, xs, asrc, adst);
    edge_alpha_kernel<<<EB, 256, 0, stream>>>(csrsrc, csrdst, csrea, asrc, adst, wd2, alpha);
    aggregate_kernel<<<NB, 256, 0, stream>>>(xs, alpha, csrsrc, offs, deg, b2, hbuf, 0);

    // mean pool
    int pool_waves = (N_NODES + 15) / 16;
    int pool_blocks = (pool_waves + 3) / 4;
    pool_kernel<<<pool_blocks, 256, 0, stream>>>(hbuf, batch, out, cnt);
    pool_div_kernel<<<N_GRAPHS, 64, 0, stream>>>(out, cnt);
}

// Round 4
// 378.181 us; speedup vs baseline: 1.4608x; 1.1167x over previous
//
#include <hip/hip_runtime.h>
#include <float.h>

#define N_NODES   50000
#define N_EDGES   800000
#define INDIM1    128
#define HC        64
#define N_GRAPHS  64
#define NEG_SLOPE 0.2f

// ---------------- CSR build ----------------

__global__ __launch_bounds__(256) void hist_kernel(const int* __restrict__ dst,
                                                   int* __restrict__ deg) {
    int e = blockIdx.x * blockDim.x + threadIdx.x;
    if (e < N_EDGES) atomicAdd(&deg[dst[e]], 1);
}

// Assign each node a contiguous edge range [beg, beg+deg) in arbitrary order:
// per-wave shfl-scan + one atomicAdd per wave.
__global__ __launch_bounds__(256) void alloc_kernel(const int* __restrict__ deg,
                                                    int* __restrict__ beg,
                                                    int* __restrict__ gcounter) {
    int i = blockIdx.x * blockDim.x + threadIdx.x;
    int lane = threadIdx.x & 63;
    int d = (i < N_NODES) ? deg[i] : 0;
    int pre = d;
    for (int off = 1; off < 64; off <<= 1) {
        int o = __shfl_up(pre, off);
        if (lane >= off) pre += o;
    }
    int total = __shfl(pre, 63);
    int base = 0;
    if (lane == 63) base = atomicAdd(gcounter, total);
    base = __shfl(base, 63);
    if (i < N_NODES) beg[i] = base + pre - d;
}

// Pack {src, edge_attr} into ONE 8B random write per edge (was 3x4B to three
// arrays = 3 dirty lines/edge -> 105MB write traffic; now 1 line/edge).
// csr_dst is not needed at all: the fused aggregate knows dst == node.
__global__ __launch_bounds__(256) void scatter_kernel(const int* __restrict__ src,
                                                      const int* __restrict__ dst,
                                                      const float* __restrict__ eattr,
                                                      const int* __restrict__ beg,
                                                      int* __restrict__ cursor,
                                                      int2* __restrict__ csr_se) {
    int e = blockIdx.x * blockDim.x + threadIdx.x;
    if (e < N_EDGES) {
        int d = dst[e];
        int pos = beg[d] + atomicAdd(&cursor[d], 1);
        csr_se[pos] = make_int2(src[e], __float_as_int(eattr[e]));
    }
}

// ---------------- per-layer kernels ----------------

__global__ void wedot_kernel(const float* __restrict__ We, const float* __restrict__ ae,
                             float* __restrict__ wd) {
    int t = threadIdx.x;   // 64
    float p = We[t] * ae[t];
    for (int off = 1; off < 16; off <<= 1) p += __shfl_xor(p, off);
    if ((t & 15) == 0) wd[t >> 4] = p;
}

// xs = x @ W; a_src/a_dst per (node, head).
template <int INDIM, int NPW>
__global__ __launch_bounds__(256) void transform_kernel(const float* __restrict__ x,
                                                        const float* __restrict__ W,
                                                        const float* __restrict__ att_s,
                                                        const float* __restrict__ att_d,
                                                        float* __restrict__ xs,
                                                        float* __restrict__ a_src,
                                                        float* __restrict__ a_dst) {
    constexpr int K4 = INDIM / 4;
    __shared__ float4 Wsh[K4 * 64];     // [k4][col]
    __shared__ float4 xsh[4][K4];       // per-wave current x row
    int t = threadIdx.x;
    for (int i = t; i < K4 * 64; i += 256) {
        int k4 = i >> 6, col = i & 63;
        Wsh[i] = make_float4(W[(4 * k4 + 0) * 64 + col], W[(4 * k4 + 1) * 64 + col],
                             W[(4 * k4 + 2) * 64 + col], W[(4 * k4 + 3) * 64 + col]);
    }
    __syncthreads();
    int w = t >> 6, lane = t & 63;
    float avs = att_s[lane], avd = att_d[lane];
    int node0 = blockIdx.x * (4 * NPW) + w * NPW;
    for (int ni = 0; ni < NPW; ++ni) {
        int node = node0 + ni;
        if (node >= N_NODES) return;   // wave-uniform
        if (lane < K4) xsh[w][lane] = ((const float4*)(x + (size_t)node * INDIM))[lane];
        float acc = 0.f;
#pragma unroll
        for (int k4 = 0; k4 < K4; ++k4) {
            float4 xv = xsh[w][k4];
            float4 wv = Wsh[k4 * 64 + lane];
            acc = fmaf(xv.x, wv.x, acc);
            acc = fmaf(xv.y, wv.y, acc);
            acc = fmaf(xv.z, wv.z, acc);
            acc = fmaf(xv.w, wv.w, acc);
        }
        xs[(size_t)node * 64 + lane] = acc;
        float ps = acc * avs;
        float pd = acc * avd;
        for (int off = 1; off < 16; off <<= 1) {
            ps += __shfl_xor(ps, off);
            pd += __shfl_xor(pd, off);
        }
        if ((lane & 15) == 0) {
            a_src[node * 4 + (lane >> 4)] = ps;
            a_dst[node * 4 + (lane >> 4)] = pd;
        }
    }
}

// FUSED attention + aggregation. One wave per node, 16-edge chunks.
// Per chunk: coalesced int2 csr load; alpha computed in-register
// (a_src[sv] gather from an 800KB L2-resident buffer + wave-uniform a_dst
// + ea*wd); online softmax via shfl; then 16 ALWAYS-UNROLLED independent
// xs row gathers (invalid slots: wgt=0, row 0 -> L1-hot, no tail branch).
__global__ __launch_bounds__(256) void aggregate_kernel(const float* __restrict__ xs,
                                                        const int2* __restrict__ csr_se,
                                                        const int* __restrict__ beg_arr,
                                                        const int* __restrict__ deg,
                                                        const float* __restrict__ a_src,
                                                        const float* __restrict__ a_dst,
                                                        const float* __restrict__ wd,
                                                        const float* __restrict__ bias,
                                                        float* __restrict__ outb,
                                                        int do_relu) {
    int w = threadIdx.x >> 6, lane = threadIdx.x & 63;
    int node = blockIdx.x * 4 + w;
    if (node >= N_NODES) return;
    int beg = beg_arr[node], end = beg + deg[node];
    const int e_idx = lane >> 2;   // 0..15: edge slot in chunk
    const int h4 = lane & 3;       // head for the softmax lanes
    const int h2 = lane >> 4;      // my output head (channel = lane & 15)

    float wdv = wd[h4];
    float adv = a_dst[node * 4 + h4];

    float m = -FLT_MAX;            // running max, head h4
    float s = 0.f;                 // partial weight sum (this lane's slots)
    float acc = 0.f;               // output accumulator, head h2

    for (int j0 = beg; j0 < end; j0 += 16) {
        int j = j0 + e_idx;
        bool v = (j < end);
        int sv = 0;
        float a = -FLT_MAX;
        if (v) {
            int2 se = csr_se[j];
            sv = se.x;
            float ea = __int_as_float(se.y);
            float as = a_src[sv * 4 + h4];          // gather, L2-resident
            a = as + adv + ea * wdv;
            a = a > 0.f ? a : NEG_SLOPE * a;
        }
        // chunk max per head over the 16 e-slots
        float cm = a;
        cm = fmaxf(cm, __shfl_xor(cm, 4));
        cm = fmaxf(cm, __shfl_xor(cm, 8));
        cm = fmaxf(cm, __shfl_xor(cm, 16));
        cm = fmaxf(cm, __shfl_xor(cm, 32));
        float mn = fmaxf(m, cm);
        float sc = __expf(m - mn);                  // rescale old state
        float wgt = __expf(a - mn);                 // 0 for invalid slots
        s = s * sc + wgt;
        m = mn;
        acc *= __shfl(sc, h2);
#pragma unroll
        for (int e = 0; e < 16; ++e) {
            float wg = __shfl(wgt, (e << 2) | h2);
            int svb = __shfl(sv, e << 2);
            acc = fmaf(wg, xs[(size_t)svb * 64 + lane], acc);
        }
    }
    s += __shfl_xor(s, 4);
    s += __shfl_xor(s, 8);
    s += __shfl_xor(s, 16);
    s += __shfl_xor(s, 32);
    float sh = __shfl(s, h2);
    float res = (sh > 0.f) ? acc / sh : 0.f;
    res += bias[lane];
    if (do_relu) res = fmaxf(res, 0.f);
    outb[(size_t)node * 64 + lane] = res;
}

// ---------------- pooling ----------------

__global__ __launch_bounds__(256) void pool_kernel(const float* __restrict__ h,
                                                   const int* __restrict__ batch,
                                                   float* __restrict__ out,
                                                   int* __restrict__ cnt) {
    int wave = (blockIdx.x * blockDim.x + threadIdx.x) >> 6;
    int lane = threadIdx.x & 63;
    int i0 = wave * 16;
    if (i0 >= N_NODES) return;
    int i1 = min(i0 + 16, N_NODES);
    float acc = 0.f;
    int c = 0;
    int gcur = batch[i0];
    for (int i = i0; i < i1; ++i) {
        int g = batch[i];
        if (g != gcur) {
            atomicAdd(&out[gcur * 64 + lane], acc);
            if (lane == 0) atomicAdd(&cnt[gcur], c);
            acc = 0.f; c = 0; gcur = g;
        }
        acc += h[i * 64 + lane];
        ++c;
    }
    atomicAdd(&out[gcur * 64 + lane], acc);
    if (lane == 0) atomicAdd(&cnt[gcur], c);
}

__global__ void pool_div_kernel(float* __restrict__ out, const int* __restrict__ cnt) {
    int g = blockIdx.x, t = threadIdx.x;
    float c = (float)max(cnt[g], 1);
    out[g * 64 + t] /= c;
}

// ---------------- launch ----------------

extern "C" void kernel_launch(void* const* d_in, const int* in_sizes, int n_in,
                              void* d_out, int out_size, void* d_ws, size_t ws_size,
                              hipStream_t stream) {
    const float* x    = (const float*)d_in[0];
    const int*   eidx = (const int*)d_in[1];
    const float* eat  = (const float*)d_in[2];
    const int*   batch= (const int*)d_in[3];
    const float* W1   = (const float*)d_in[4];
    const float* We1  = (const float*)d_in[5];
    const float* as1  = (const float*)d_in[6];
    const float* ad1  = (const float*)d_in[7];
    const float* ae1  = (const float*)d_in[8];
    const float* b1   = (const float*)d_in[9];
    const float* W2   = (const float*)d_in[10];
    const float* We2  = (const float*)d_in[11];
    const float* as2  = (const float*)d_in[12];
    const float* ad2  = (const float*)d_in[13];
    const float* ae2  = (const float*)d_in[14];
    const float* b2   = (const float*)d_in[15];
    const int* src  = eidx;             // edge_index[0]
    const int* dstp = eidx + N_EDGES;   // edge_index[1]
    float* out = (float*)d_out;

    char* p = (char*)d_ws;
    auto alloc = [&](size_t bytes) {
        char* r = p;
        p += (bytes + 255) & ~(size_t)255;
        return r;
    };
    float* xs     = (float*)alloc((size_t)N_NODES * 64 * 4);
    float* hbuf   = (float*)alloc((size_t)N_NODES * 64 * 4);
    float* asrc   = (float*)alloc((size_t)N_NODES * 4 * 4);
    float* adst   = (float*)alloc((size_t)N_NODES * 4 * 4);
    float* wd1    = (float*)alloc(64);
    float* wd2    = (float*)alloc(64);
    int*   deg    = (int*)alloc((size_t)N_NODES * 4);
    int*   offs   = (int*)alloc((size_t)N_NODES * 4);
    int*   cur    = (int*)alloc((size_t)N_NODES * 4);
    int2*  csrse  = (int2*)alloc((size_t)N_EDGES * 8);
    int*   cnt    = (int*)alloc(64 * 4);
    int*   gctr   = (int*)alloc(256);

    hipMemsetAsync(deg, 0, (size_t)N_NODES * 4, stream);
    hipMemsetAsync(cur, 0, (size_t)N_NODES * 4, stream);
    hipMemsetAsync(cnt, 0, 64 * 4, stream);
    hipMemsetAsync(gctr, 0, 256, stream);
    hipMemsetAsync(d_out, 0, (size_t)N_GRAPHS * 64 * 4, stream);

    const int EB = (N_EDGES + 255) / 256;
    const int NB = (N_NODES + 3) / 4;
    const int AB = (N_NODES + 255) / 256;

    hist_kernel<<<EB, 256, 0, stream>>>(dstp, deg);
    alloc_kernel<<<AB, 256, 0, stream>>>(deg, offs, gctr);
    scatter_kernel<<<EB, 256, 0, stream>>>(src, dstp, eat, offs, cur, csrse);
    wedot_kernel<<<1, 64, 0, stream>>>(We1, ae1, wd1);
    wedot_kernel<<<1, 64, 0, stream>>>(We2, ae2, wd2);

    // layer 1
    const int NPW = 8;
    const int TB = (N_NODES + 4 * NPW - 1) / (4 * NPW);
    transform_kernel<INDIM1, NPW><<<TB, 256, 0, stream>>>(x, W1, as1, ad1, xs, asrc, adst);
    aggregate_kernel<<<NB, 256, 0, stream>>>(xs, csrse, offs, deg, asrc, adst, wd1, b1, hbuf, 1);

    // layer 2
    transform_kernel<HC, NPW><<<TB, 256, 0, stream>>>(hbuf, W2, as2, ad2, xs, asrc, adst);
    aggregate_kernel<<<NB, 256, 0, stream>>>(xs, csrse, offs, deg, asrc, adst, wd2, b2, hbuf, 0);

    // mean pool
    int pool_waves = (N_NODES + 15) / 16;
    int pool_blocks = (pool_waves + 3) / 4;
    pool_kernel<<<pool_blocks, 256, 0, stream>>>(hbuf, batch, out, cnt);
    pool_div_kernel<<<N_GRAPHS, 64, 0, stream>>>(out, cnt);
}